// Round 5
// baseline (1912.177 us; speedup 1.0000x reference)
//
#include <hip/hip_runtime.h>

#define T_SEQ 2048
#define DIN   16
#define HH    80
#define NTHR  512
#define NBLK  256
#define BT    2
#define ROWE  160   // f16 per row: [h1 0:80 | h2 80:160]

#define L2E   1.44269504088896340736f

typedef _Float16 f16x8 __attribute__((ext_vector_type(8)));
typedef float    f32x4 __attribute__((ext_vector_type(4)));
typedef _Float16 h2v   __attribute__((ext_vector_type(2)));

__device__ __forceinline__ float rcp_fast(float x){ return __builtin_amdgcn_rcpf(x); }
__device__ __forceinline__ float ex2(float x){
#if __has_builtin(__builtin_amdgcn_exp2f)
    return __builtin_amdgcn_exp2f(x);
#else
    return exp2f(x);
#endif
}

static __device__ __forceinline__ float fdot2f(float w, float h, float acc) {
    return __builtin_amdgcn_fdot2(__builtin_bit_cast(h2v, w), __builtin_bit_cast(h2v, h), acc, false);
}
static __device__ __forceinline__ float pk2(float a, float b) {
    h2v v; v[0] = (_Float16)a; v[1] = (_Float16)b;
    return __builtin_bit_cast(float, v);
}
static __device__ __forceinline__ float4 pkf4(float4 a, float4 b, float sc){
    return make_float4(pk2(a.x*sc,a.y*sc), pk2(a.z*sc,a.w*sc),
                       pk2(b.x*sc,b.y*sc), pk2(b.z*sc,b.w*sc));
}
static __device__ __forceinline__ float qswap1(float v){
    int r = __builtin_amdgcn_update_dpp(0, __builtin_bit_cast(int, v), 0xB1, 0xF, 0xF, true);
    return __builtin_bit_cast(float, r);
}

#define MF(av, bv, cv) __builtin_amdgcn_mfma_f32_16x16x32_f16(av, bv, cv, 0, 0, 0)
#define AF(i) __builtin_bit_cast(f16x8, P[i])
// L2 tile-slot: 5 K-chunks over concat [h1|h2], bias pre-loaded in C
#define L2SLOT(acc, s) { acc = MF(AF(s*5+0), BM0, Q[s]); acc = MF(AF(s*5+1), BM1, acc); \
                         acc = MF(AF(s*5+2), BM2, acc); acc = MF(AF(s*5+3), BM3, acc); \
                         acc = MF(AF(s*5+4), BM4, acc); }
#define DG4(acc, Wq, Hq) { acc = fdot2f(Wq.x, Hq.x, acc); acc = fdot2f(Wq.y, Hq.y, acc); \
                           acc = fdot2f(Wq.z, Hq.z, acc); acc = fdot2f(Wq.w, Hq.w, acc); }
#define PIN4(v) asm volatile("" : "+v"(v.x), "+v"(v.y), "+v"(v.z), "+v"(v.w))

__global__
__attribute__((amdgpu_flat_work_group_size(NTHR, NTHR)))
__attribute__((amdgpu_waves_per_eu(2, 2)))
void lstm2_hyb(
    const float* __restrict__ x,
    const float* __restrict__ W_ih1, const float* __restrict__ W_hh1,
    const float* __restrict__ b_ih1, const float* __restrict__ b_hh1,
    const float* __restrict__ W_ih2, const float* __restrict__ W_hh2,
    const float* __restrict__ b_ih2, const float* __restrict__ b_hh2,
    const float* __restrict__ W_d,   const float* __restrict__ b_d,
    float* __restrict__ out)
{
    __shared__ __align__(16) _Float16 HB[2][BT][ROWE];   // [parity][batch][h1|h2]
    __shared__ __align__(16) _Float16 XB[2][BT][DIN];    // staged x, per parity

    const int t    = threadIdx.x;
    const int lane = t & 63;
    const int wv   = t >> 6;              // wv&3 = SIMD (round-robin)
    const int m16  = lane & 15;
    const int kgrp = lane >> 4;
    const int b0   = blockIdx.x * BT;

    // roles: wv 0-2 = L1 via fdot2 (VALU pipe); wv 4-7 = L2 via MFMA (matrix pipe),
    // one per SIMD; wv 3 idle; x-stager = wv2 lanes 32-63 (hides vmcnt under fdot2).
    const int  idx   = (wv << 6) | lane;       // L1 lane id
    const int  uL    = idx >> 1;               // L1 unit 0..79
    const int  sL    = idx & 1;                // L1 K-half
    const bool actL  = (wv < 3) && (idx < 160);

    // ---- overlaid persistent registers: L1 = P[0..23]+Q[0]; L2 = P[0..24]+Q[0..4] ----
    float4 P[25];
    f32x4  Q[5];

    if (actL) {
        #pragma unroll
        for (int g = 0; g < 4; ++g) {
            const float sc = (g == 2) ? (2.f*L2E) : L2E;   // tanh gate: 2*log2e
            const int grow = g*HH + uL;
            const float4* Ph = (const float4*)(W_hh1 + (size_t)grow*HH + 40*sL);
            #pragma unroll
            for (int c = 0; c < 5; ++c) P[g*6 + c] = pkf4(Ph[2*c], Ph[2*c+1], sc);
            const float4* Px = (const float4*)(W_ih1 + (size_t)grow*DIN + 8*sL);
            P[g*6 + 5] = pkf4(Px[0], Px[1], sc);
            Q[0][g] = (b_ih1[grow] + b_hh1[grow]) * sc;
        }
    } else if (wv >= 4) {
        const int uloc = 20*(wv - 4);
        const int g  = m16 & 3;
        const int ut = m16 >> 2;
        const float sc = (g == 2) ? (2.f*L2E) : L2E;
        #pragma unroll
        for (int s = 0; s < 5; ++s) {
            const int grow = g*HH + (uloc + 4*s + ut);
            #pragma unroll
            for (int c = 0; c < 5; ++c) {
                f16x8 a;
                #pragma unroll
                for (int j = 0; j < 8; ++j) {
                    const int kk = 32*c + 8*kgrp + j;
                    const float v = (kk < HH) ? W_ih2[(size_t)grow*HH + kk]
                                              : W_hh2[(size_t)grow*HH + (kk - HH)];
                    a[j] = (_Float16)(v * sc);
                }
                P[s*5 + c] = __builtin_bit_cast(float4, a);
            }
            const int u = uloc + 4*s + kgrp;
            Q[s][0] = (b_ih2[       u] + b_hh2[       u]) * L2E;
            Q[s][1] = (b_ih2[  HH + u] + b_hh2[  HH + u]) * L2E;
            Q[s][2] = (b_ih2[2*HH + u] + b_hh2[2*HH + u]) * (2.f*L2E);
            Q[s][3] = (b_ih2[3*HH + u] + b_hh2[3*HH + u]) * L2E;
        }
    }

    // L2 merged-epilogue identity (cols replicated mod 2)
    const int  uloc2   = (wv >= 4) ? 20*(wv - 4) : 0;
    const int  te      = m16 >> 1;
    const bool act_ep  = (m16 < 10);
    const int  unit_ep = uloc2 + 4*(act_ep ? te : 0) + kgrp;
    const int  batch_ep = lane & 1;

    // ---- zero h state (both parities), prestage x(0), prime prefetch regs ----
    for (int i = t; i < 2*BT*ROWE; i += NTHR) ((_Float16*)HB)[i] = (_Float16)0.f;

    const int  xbn = (lane - 32) >> 4;        // stager lanes 32-63: batch 0/1
    const int  xch = lane & 15;
    const float* xptr = x + ((size_t)(b0 + xbn) * T_SEQ) * DIN + xch;
    float xa = 0.f, xbv = 0.f, xcv = 0.f;
    if (wv == 2 && lane >= 32) {
        XB[0][xbn][xch] = (_Float16)xptr[0];
        xa  = xptr[1*DIN];
        xbv = xptr[2*DIN];
        xcv = xptr[3*DIN];
    }
    __syncthreads();

    float cA = 0.f, cB = 0.f;   // L1 lanes: cell per batch; L2 lanes: use cA only

    // window k: L1 computes h1(k) from [x(k),h1(k-1)]@pb -> h1@nb
    //           L2 computes h2(k-1) from [h1(k-1),h2(k-2)]@pb -> h2@nb
    #pragma unroll 1
    for (int k = 0; k <= T_SEQ; ++k) {
        const int pb = k & 1, nb = pb ^ 1;

        if (wv == 2 && lane >= 32) {          // stage x(k+1) -> nb; 3-deep prefetch
            XB[nb][xbn][xch] = (_Float16)xa;
            xa = xbv; xbv = xcv;
            const int tn = (k + 4 < T_SEQ) ? (k + 4) : (T_SEQ - 1);
            xcv = xptr[(size_t)tn * DIN];
        }

        if (wv < 3) {                          // ---------------- L1 (fdot2, VALU pipe)
            if (k < T_SEQ && idx < 160) {
                PIN4(P[0]);  PIN4(P[1]);  PIN4(P[2]);  PIN4(P[3]);  PIN4(P[4]);  PIN4(P[5]);
                PIN4(P[6]);  PIN4(P[7]);  PIN4(P[8]);  PIN4(P[9]);  PIN4(P[10]); PIN4(P[11]);
                PIN4(P[12]); PIN4(P[13]); PIN4(P[14]); PIN4(P[15]); PIN4(P[16]); PIN4(P[17]);
                PIN4(P[18]); PIN4(P[19]); PIN4(P[20]); PIN4(P[21]); PIN4(P[22]); PIN4(P[23]);
                #pragma unroll
                for (int b = 0; b < BT; ++b) {
                    const _Float16* hb = &HB[pb][b][40*sL];
                    const float4 h0 = ((const float4*)hb)[0], h1 = ((const float4*)hb)[1],
                                 h2 = ((const float4*)hb)[2], h3 = ((const float4*)hb)[3],
                                 h4 = ((const float4*)hb)[4];
                    const float4 xv = *(const float4*)(&XB[pb][b][8*sL]);
                    float ai=0.f, af=0.f, ag=0.f, ao=0.f;
                    DG4(ai,P[0],h0)  DG4(ai,P[1],h1)  DG4(ai,P[2],h2)  DG4(ai,P[3],h3)  DG4(ai,P[4],h4)  DG4(ai,P[5],xv)
                    DG4(af,P[6],h0)  DG4(af,P[7],h1)  DG4(af,P[8],h2)  DG4(af,P[9],h3)  DG4(af,P[10],h4) DG4(af,P[11],xv)
                    DG4(ag,P[12],h0) DG4(ag,P[13],h1) DG4(ag,P[14],h2) DG4(ag,P[15],h3) DG4(ag,P[16],h4) DG4(ag,P[17],xv)
                    DG4(ao,P[18],h0) DG4(ao,P[19],h1) DG4(ao,P[20],h2) DG4(ao,P[21],h3) DG4(ao,P[22],h4) DG4(ao,P[23],xv)
                    ai += qswap1(ai); af += qswap1(af); ag += qswap1(ag); ao += qswap1(ao);
                    if (sL == 0) {
                        float& cs = b ? cB : cA;
                        const float iv = rcp_fast(1.f + ex2(-(ai + Q[0][0])));
                        const float fv = rcp_fast(1.f + ex2(-(af + Q[0][1])));
                        const float gv = 1.f - 2.f*rcp_fast(1.f + ex2(ag + Q[0][2]));
                        const float ov = rcp_fast(1.f + ex2(-(ao + Q[0][3])));
                        cs = fv*cs + iv*gv;
                        const float tc = 1.f - 2.f*rcp_fast(1.f + ex2(cs * (2.f*L2E)));
                        HB[nb][b][uL] = (_Float16)(ov * tc);
                    }
                }
            }
        } else if (wv >= 4) {                  // ---------------- L2 (MFMA, matrix pipe)
            if (k >= 1) {
                const _Float16* rb = &HB[pb][lane & 1][0];   // col n <- batch n&1
                const f16x8 BM0 = *(const f16x8*)(rb +       8*kgrp);   // h1[0:32)
                const f16x8 BM1 = *(const f16x8*)(rb +  32 + 8*kgrp);   // h1[32:64)
                const f16x8 BM2 = *(const f16x8*)(rb +  64 + 8*kgrp);   // h1[64:80)|h2[0:16)
                const f16x8 BM3 = *(const f16x8*)(rb +  96 + 8*kgrp);   // h2[16:48)
                const f16x8 BM4 = *(const f16x8*)(rb + 128 + 8*kgrp);   // h2[48:80)
                f32x4 acc0, acc1, acc2, acc3, acc4;
                L2SLOT(acc0, 0) L2SLOT(acc1, 1) L2SLOT(acc2, 2)
                L2SLOT(acc3, 3) L2SLOT(acc4, 4)

                float M0 = acc0[0], M1 = acc0[1], M2 = acc0[2], M3 = acc0[3];
                if (te == 1) { M0 = acc1[0]; M1 = acc1[1]; M2 = acc1[2]; M3 = acc1[3]; }
                if (te == 2) { M0 = acc2[0]; M1 = acc2[1]; M2 = acc2[2]; M3 = acc2[3]; }
                if (te == 3) { M0 = acc3[0]; M1 = acc3[1]; M2 = acc3[2]; M3 = acc3[3]; }
                if (te == 4) { M0 = acc4[0]; M1 = acc4[1]; M2 = acc4[2]; M3 = acc4[3]; }

                const float iv = rcp_fast(1.f + ex2(-M0));
                const float fv = rcp_fast(1.f + ex2(-M1));
                const float gv = 1.f - 2.f*rcp_fast(1.f + ex2(M2));
                const float ov = rcp_fast(1.f + ex2(-M3));
                cA = fv*cA + iv*gv;
                const float tc = 1.f - 2.f*rcp_fast(1.f + ex2(cA * (2.f*L2E)));
                if (act_ep)
                    HB[nb][batch_ep][HH + unit_ep] = (_Float16)(ov * tc);
            }
        }
        __syncthreads();
    }

    // ---- dense head: out[b] = W_d . h2(T-1) + b_d ; h2(T-1) in parity 1 ----
    if (wv == 0) {
        float a0 = 0.f, a1 = 0.f;
        for (int u = lane; u < HH; u += 64) {
            const float wd = W_d[u];
            a0 += wd * (float)HB[1][0][HH + u];
            a1 += wd * (float)HB[1][1][HH + u];
        }
        #pragma unroll
        for (int off = 32; off > 0; off >>= 1) {
            a0 += __shfl_down(a0, off);
            a1 += __shfl_down(a1, off);
        }
        if (lane == 0) { out[b0] = a0 + b_d[0]; out[b0 + 1] = a1 + b_d[0]; }
    }
}

extern "C" void kernel_launch(void* const* d_in, const int* in_sizes, int n_in,
                              void* d_out, int out_size, void* d_ws, size_t ws_size,
                              hipStream_t stream) {
    const float* x     = (const float*)d_in[0];
    const float* W_ih1 = (const float*)d_in[1];
    const float* W_hh1 = (const float*)d_in[2];
    const float* b_ih1 = (const float*)d_in[3];
    const float* b_hh1 = (const float*)d_in[4];
    const float* W_ih2 = (const float*)d_in[5];
    const float* W_hh2 = (const float*)d_in[6];
    const float* b_ih2 = (const float*)d_in[7];
    const float* b_hh2 = (const float*)d_in[8];
    const float* W_d   = (const float*)d_in[9];
    const float* b_d   = (const float*)d_in[10];

    lstm2_hyb<<<NBLK, NTHR, 0, stream>>>(x, W_ih1, W_hh1, b_ih1, b_hh1,
                                         W_ih2, W_hh2, b_ih2, b_hh2,
                                         W_d, b_d, (float*)d_out);
}

// Round 6
// 1458.992 us; speedup vs baseline: 1.3106x; 1.3106x over previous
//
#include <hip/hip_runtime.h>

#define T_SEQ 2048
#define DIN   16
#define HH    80
#define NTHR  512
#define NBLK  256
#define BT    2
#define ROWE  160   // f16 per row: [h1 0:80 | h2 80:160]
#define XRT   512   // x-ring timesteps (4 chunks x 128)
#define XCH   128   // refill chunk

#define L2E   1.44269504088896340736f

typedef _Float16 f16x8 __attribute__((ext_vector_type(8)));
typedef float    f32x4 __attribute__((ext_vector_type(4)));

__device__ __forceinline__ float rcp_fast(float x){ return __builtin_amdgcn_rcpf(x); }
__device__ __forceinline__ float ex2(float x){
#if __has_builtin(__builtin_amdgcn_exp2f)
    return __builtin_amdgcn_exp2f(x);
#else
    return exp2f(x);
#endif
}

#define MF(av, bv, cv) __builtin_amdgcn_mfma_f32_16x16x32_f16(av, bv, cv, 0, 0, 0)
// L1 slot: 3 K-chunks over [x(16)|h1(80)]; bias pre-loaded in C
#define L1SLOT(acc, s) { acc = MF(A[s][0], B0, Q[s]); acc = MF(A[s][1], B1, acc); \
                         acc = MF(A[s][2], B2, acc); }
// L2 slot: 5 K-chunks over [h1(80)|h2(80)]; bias pre-loaded in C
#define L2SLOT(acc, s) { acc = MF(A[s][0], B0, Q[s]); acc = MF(A[s][1], B1, acc); \
                         acc = MF(A[s][2], B2, acc); acc = MF(A[s][3], B3, acc); \
                         acc = MF(A[s][4], B4, acc); }

__global__
__attribute__((amdgpu_flat_work_group_size(NTHR, NTHR)))
__attribute__((amdgpu_waves_per_eu(2, 2)))
void lstm2_mfma(
    const float* __restrict__ x,
    const float* __restrict__ W_ih1, const float* __restrict__ W_hh1,
    const float* __restrict__ b_ih1, const float* __restrict__ b_hh1,
    const float* __restrict__ W_ih2, const float* __restrict__ W_hh2,
    const float* __restrict__ b_ih2, const float* __restrict__ b_hh2,
    const float* __restrict__ W_d,   const float* __restrict__ b_d,
    float* __restrict__ out)
{
    __shared__ __align__(16) _Float16 HB[2][BT][ROWE];     // [parity][batch][h1|h2]
    __shared__ __align__(16) _Float16 XR[XRT][BT][DIN];    // x ring, f16 (32 KB)

    const int t    = threadIdx.x;
    const int lane = t & 63;
    const int wv   = t >> 6;              // 0..7 ; wv&3 = SIMD
    const bool isL1w = (wv < 4);
    const int m16  = lane & 15;
    const int kgrp = lane >> 4;           // 0..3
    const int b0   = blockIdx.x * BT;

    const int uloc = isL1w ? 20*wv : 20*(wv-4);   // first unit of this wave's 5 tiles

    // ---------------- stationary A fragments + bias-in-C ----------------
    // A row m in tile: unit = 4*tile + (m>>2), gate = m&3 (i,f,g,o interleaved)
    // C rows: 4*kgrp + gate -> Q[s] = biases for unit (uloc+4s+kgrp), pre-scaled
    f16x8 A[5][5];
    f32x4 Q[5];
    {
        const int g  = m16 & 3;
        const int ut = m16 >> 2;
        const float sc = (g == 2) ? (2.f*L2E) : L2E;       // tanh gate: 2*log2e
        #pragma unroll
        for (int s = 0; s < 5; ++s) {
            const int grow = g*HH + (uloc + 4*s + ut);
            #pragma unroll
            for (int c = 0; c < 5; ++c) {
                if (isL1w && c >= 3) continue;             // L1 K=96: 3 chunks
                f16x8 a;
                #pragma unroll
                for (int j = 0; j < 8; ++j) {
                    const int kk = 32*c + 8*kgrp + j;
                    const float v = isL1w
                        ? ((kk < DIN) ? W_ih1[(size_t)grow*DIN + kk]
                                      : W_hh1[(size_t)grow*HH + (kk - DIN)])
                        : ((kk < HH)  ? W_ih2[(size_t)grow*HH + kk]
                                      : W_hh2[(size_t)grow*HH + (kk - HH)]);
                    a[j] = (_Float16)(v * sc);
                }
                A[s][c] = a;
            }
            const int u = uloc + 4*s + kgrp;
            const float* bI = isL1w ? b_ih1 : b_ih2;
            const float* bH = isL1w ? b_hh1 : b_hh2;
            f32x4 bb;
            bb[0] = (bI[       u] + bH[       u]) * L2E;
            bb[1] = (bI[  HH + u] + bH[  HH + u]) * L2E;
            bb[2] = (bI[2*HH + u] + bH[2*HH + u]) * (2.f*L2E);
            bb[3] = (bI[3*HH + u] + bH[3*HH + u]) * L2E;
            Q[s] = bb;
        }
    }

    // ---------------- merged-epilogue per-lane identity ----------------
    const int  te      = m16 >> 1;
    const bool act_ep  = (m16 < 10);
    const int  unit_ep = uloc + 4*(act_ep ? te : 0) + kgrp;
    const int  seg     = isL1w ? 0 : HH;
    const int  batch_ep = lane & 1;

    // ---------------- zero h state; preload x chunks 0,1 into ring ----------------
    for (int i = t; i < 2*BT*ROWE; i += NTHR) ((_Float16*)HB)[i] = (_Float16)0.f;

    // refill mapping: thread -> (toff 0..127, xb, c8); 128*2*2 = 512 = NTHR
    const int toff = t >> 2, xb = (t >> 1) & 1, c8 = t & 1;
    const float* xsrc = x + ((size_t)(b0 + xb) * T_SEQ) * DIN + c8*8;
    #pragma unroll
    for (int c0 = 0; c0 < 2*XCH; c0 += XCH) {
        const int tt = c0 + toff;
        const float4 va = *(const float4*)(xsrc + (size_t)tt * DIN);
        const float4 vb = *(const float4*)(xsrc + (size_t)tt * DIN + 4);
        f16x8 h;
        h[0]=(_Float16)va.x; h[1]=(_Float16)va.y; h[2]=(_Float16)va.z; h[3]=(_Float16)va.w;
        h[4]=(_Float16)vb.x; h[5]=(_Float16)vb.y; h[6]=(_Float16)vb.z; h[7]=(_Float16)vb.w;
        *(f16x8*)&XR[tt][xb][c8*8] = h;
    }
    __syncthreads();

    float cst = 0.f;                    // cell state for this lane's (unit,batch)
    float4 xva{}, xvb{};                // T14 split: loads issued one window early
    int pend_tt = -1;

    // window k: L1 computes h1(k) from [x(k)|h1(k-1)]@pb -> h1@nb
    //           L2 computes h2(k-1) from [h1(k-1)|h2(k-2)]@pb -> h2@nb
    #pragma unroll 1
    for (int k = 0; k <= T_SEQ; ++k) {
        const int pb = k & 1, nb = pb ^ 1;

        // ---- x-ring maintenance: issue loads at k%128==0; write-back at k%128==1 ----
        if ((k & (XCH-1)) == 0 && (k + 2*XCH + XCH) <= T_SEQ + XCH) {  // k+384 <= 2048
            const int tt = k + 2*XCH + toff;
            if (tt < T_SEQ) {
                xva = *(const float4*)(xsrc + (size_t)tt * DIN);
                xvb = *(const float4*)(xsrc + (size_t)tt * DIN + 4);
                pend_tt = tt;
            }
        } else if ((k & (XCH-1)) == 1 && pend_tt >= 0) {
            f16x8 h;
            h[0]=(_Float16)xva.x; h[1]=(_Float16)xva.y; h[2]=(_Float16)xva.z; h[3]=(_Float16)xva.w;
            h[4]=(_Float16)xvb.x; h[5]=(_Float16)xvb.y; h[6]=(_Float16)xvb.z; h[7]=(_Float16)xvb.w;
            *(f16x8*)&XR[pend_tt & (XRT-1)][xb][c8*8] = h;
            pend_tt = -1;
        }

        const bool act = isL1w ? (k < T_SEQ) : (k >= 1);
        if (act) {
            const _Float16* hb = &HB[pb][lane & 1][0];     // B col n <- batch n&1
            f32x4 acc0, acc1, acc2, acc3, acc4;
            if (isL1w) {
                // B0: kgrp<2 -> x(k) from ring ; kgrp>=2 -> h1[0:16)
                const _Float16* xrb = &XR[k & (XRT-1)][lane & 1][0];
                const _Float16* p0  = (kgrp < 2) ? (xrb + 8*kgrp) : (hb + 8*kgrp - 16);
                const f16x8 B0 = *(const f16x8*)p0;
                const f16x8 B1 = *(const f16x8*)(hb + 16 + 8*kgrp);   // h1[16:48)
                const f16x8 B2 = *(const f16x8*)(hb + 48 + 8*kgrp);   // h1[48:80)
                L1SLOT(acc0, 0) L1SLOT(acc1, 1) L1SLOT(acc2, 2)
                L1SLOT(acc3, 3) L1SLOT(acc4, 4)
            } else {
                const f16x8 B0 = *(const f16x8*)(hb +       8*kgrp);  // h1[0:32)
                const f16x8 B1 = *(const f16x8*)(hb +  32 + 8*kgrp);  // h1[32:64)
                const f16x8 B2 = *(const f16x8*)(hb +  64 + 8*kgrp);  // h1[64:80)|h2[0:16)
                const f16x8 B3 = *(const f16x8*)(hb +  96 + 8*kgrp);  // h2[16:48)
                const f16x8 B4 = *(const f16x8*)(hb + 128 + 8*kgrp);  // h2[48:80)
                L2SLOT(acc0, 0) L2SLOT(acc1, 1) L2SLOT(acc2, 2)
                L2SLOT(acc3, 3) L2SLOT(acc4, 4)
            }

            // in-register merge: pick own slot's (i,f,g,o)
            float M0 = acc0[0], M1 = acc0[1], M2 = acc0[2], M3 = acc0[3];
            if (te == 1) { M0 = acc1[0]; M1 = acc1[1]; M2 = acc1[2]; M3 = acc1[3]; }
            if (te == 2) { M0 = acc2[0]; M1 = acc2[1]; M2 = acc2[2]; M3 = acc2[3]; }
            if (te == 3) { M0 = acc3[0]; M1 = acc3[1]; M2 = acc3[2]; M3 = acc3[3]; }
            if (te == 4) { M0 = acc4[0]; M1 = acc4[1]; M2 = acc4[2]; M3 = acc4[3]; }

            // activations (bias + log2e already folded into C-init / weights)
            const float iv = rcp_fast(1.f + ex2(-M0));
            const float fv = rcp_fast(1.f + ex2(-M1));
            const float gv = 1.f - 2.f*rcp_fast(1.f + ex2(M2));
            const float ov = rcp_fast(1.f + ex2(-M3));
            cst = fv*cst + iv*gv;
            const float tc = 1.f - 2.f*rcp_fast(1.f + ex2(cst * (2.f*L2E)));
            if (act_ep)
                HB[nb][batch_ep][seg + unit_ep] = (_Float16)(ov * tc);
        }
        __syncthreads();
    }

    // ---- dense head: out[b] = W_d . h2(T-1) + b_d ; h2(T-1) in parity 1 ----
    if (wv == 0) {
        float a0 = 0.f, a1 = 0.f;
        for (int u = lane; u < HH; u += 64) {
            const float wd = W_d[u];
            a0 += wd * (float)HB[1][0][HH + u];
            a1 += wd * (float)HB[1][1][HH + u];
        }
        #pragma unroll
        for (int off = 32; off > 0; off >>= 1) {
            a0 += __shfl_down(a0, off);
            a1 += __shfl_down(a1, off);
        }
        if (lane == 0) { out[b0] = a0 + b_d[0]; out[b0 + 1] = a1 + b_d[0]; }
    }
}

extern "C" void kernel_launch(void* const* d_in, const int* in_sizes, int n_in,
                              void* d_out, int out_size, void* d_ws, size_t ws_size,
                              hipStream_t stream) {
    const float* x     = (const float*)d_in[0];
    const float* W_ih1 = (const float*)d_in[1];
    const float* W_hh1 = (const float*)d_in[2];
    const float* b_ih1 = (const float*)d_in[3];
    const float* b_hh1 = (const float*)d_in[4];
    const float* W_ih2 = (const float*)d_in[5];
    const float* W_hh2 = (const float*)d_in[6];
    const float* b_ih2 = (const float*)d_in[7];
    const float* b_hh2 = (const float*)d_in[8];
    const float* W_d   = (const float*)d_in[9];
    const float* b_d   = (const float*)d_in[10];

    lstm2_mfma<<<NBLK, NTHR, 0, stream>>>(x, W_ih1, W_hh1, b_ih1, b_hh1,
                                          W_ih2, W_hh2, b_ih2, b_hh2,
                                          W_d, b_d, (float*)d_out);
}